// Round 6
// baseline (1013.366 us; speedup 1.0000x reference)
//
#include <hip/hip_runtime.h>

#define NN   4096
#define KNBR 8
#define DF   240
#define SUBW 8    // candidate sub-ranges (waves) per kNN scan block
#define QPB  64   // queries per kNN block
#define NQRT 4    // candidate quarters (blocks per query-chunk)

// Branchless sorted-top-8 insert (strict <, stable for ascending-j scans).
// Distances via med3 identity: inserting v into sorted ascending a[0..7]
// (dropping a[7]) is r[0]=min(a[0],v), r[k]=med3(a[k-1],a[k],v).
//   v >= a[k]           -> med3 = a[k]    (no shift)
//   a[k-1] <= v < a[k]  -> med3 = v      (insert here)
//   v < a[k-1]          -> med3 = a[k-1] (shift down)
// Works with 3e38 sentinels. Indices via cmp+cndmask on precomputed masks.
// In-place descending k so a[k-1]/bi[k-1] are still old values when read.
__device__ __forceinline__ void insert8(float d2, int j, float bd[KNBR],
                                        int bi[KNBR]) {
  bool c[KNBR];
#pragma unroll
  for (int k = 0; k < KNBR; k++) c[k] = d2 < bd[k];
#pragma unroll
  for (int k = KNBR - 1; k >= 1; k--) {
    bd[k] = __builtin_amdgcn_fmed3f(bd[k - 1], bd[k], d2);
    bi[k] = c[k] ? (c[k - 1] ? bi[k - 1] : j) : bi[k];
  }
  bd[0] = fminf(bd[0], d2);
  bi[0] = c[0] ? j : bi[0];
}

// ---------------------------------------------------------------------------
// Kernel A: fuse weights.
//   WA = sA * (W2 @ L0)   (32x64)   ws[0..2048)
//   WB = sB * (W1 @ L1)   (64x32)   ws[2048..4096)
//   WC = sC * (W4 @ L1)   (16x32)   ws[4096..4608)
//   WD = sD * (W3 @ L2)   (32x16)   ws[4608..5120)
// ---------------------------------------------------------------------------
__global__ __launch_bounds__(256) void fuse_w(
    const float* __restrict__ W1, const float* __restrict__ W2,
    const float* __restrict__ W3, const float* __restrict__ W4,
    const float* __restrict__ L0, const float* __restrict__ L1,
    const float* __restrict__ L2, float* __restrict__ Wf) {
  const float sA = 0.012757759076995719f;  // sqrt(1/96)/8
  const float sB = 0.019764235376052370f;  // 1/sqrt(80*32)
  const float sC = 0.034232659844072875f;  // sqrt(3)/sqrt(80*32)
  const float sD = 0.098821176880261850f;  // sqrt(5/32)/4
  int idx = blockIdx.x * 256 + threadIdx.x;
  if (idx < 2048) {                       // WA: (32x64) = W2(32x64) @ L0(64x64)
    int u = idx >> 6, c = idx & 63;
    float a = 0.f;
#pragma unroll 8
    for (int m = 0; m < 64; m++) a += W2[u * 64 + m] * L0[m * 64 + c];
    Wf[idx] = sA * a;
  } else if (idx < 4096) {                // WB: (64x32) = W1(64x32) @ L1(32x32)
    int t = idx - 2048;
    int u = t >> 5, c = t & 31;
    float a = 0.f;
#pragma unroll 8
    for (int m = 0; m < 32; m++) a += W1[u * 32 + m] * L1[m * 32 + c];
    Wf[idx] = sB * a;
  } else if (idx < 4608) {                // WC: (16x32) = W4(16x32) @ L1(32x32)
    int t = idx - 4096;
    int u = t >> 5, c = t & 31;
    float a = 0.f;
#pragma unroll 8
    for (int m = 0; m < 32; m++) a += W4[u * 32 + m] * L1[m * 32 + c];
    Wf[idx] = sC * a;
  } else if (idx < 5120) {                // WD: (32x16) = W3(32x16) @ L2(16x16)
    int t = idx - 4608;
    int u = t >> 4, c = t & 15;
    float a = 0.f;
#pragma unroll 8
    for (int m = 0; m < 16; m++) a += W3[u * 16 + m] * L2[m * 16 + c];
    Wf[idx] = sD * a;
  }
}

// ---------------------------------------------------------------------------
// Kernel B1: kNN scan. grid = B*64*NQRT = 1024 blocks, 512 threads (8 waves).
//   lane (qi)  = query (64 per chunk)
//   wave (sub) = 128-candidate sub-range within this block's quarter
// Fully branchless inner loop (~44 VALU/iter): candidate coords are
// wave-uniform loads; self-exclusion via cndmask to 3e38; top-8 via insert8.
// Partial lists padded to stride 9 (gcd(9,32)=1) -> conflict-free LDS.
// ---------------------------------------------------------------------------
__global__ __launch_bounds__(512) void knn_scan(
    const float* __restrict__ coords, float* __restrict__ qd,
    int* __restrict__ qj) {
  __shared__ float pd[SUBW][QPB][KNBR + 1];        // 18 KB, stride-9 pad
  __shared__ int   pi[SUBW][QPB][KNBR + 1];        // 18 KB
  const int blk = blockIdx.x;
  const int b = blk >> 8;                // 256 blocks per batch
  const int chunk = (blk >> 2) & 63;     // query chunk (64 queries)
  const int quarter = blk & 3;           // candidate quarter (1024 cands)
  const int qi  = threadIdx.x & 63;
  const int sub = threadIdx.x >> 6;
  const int iq  = chunk * 64 + qi;       // batch-local query id
  const float* cb = coords + (size_t)b * NN * 3;
  const float qx = cb[iq * 3 + 0], qy = cb[iq * 3 + 1], qz = cb[iq * 3 + 2];
  float bd[KNBR];
  int bi[KNBR];
#pragma unroll
  for (int k = 0; k < KNBR; k++) { bd[k] = 3.0e38f; bi[k] = 0; }
  const int j0 = quarter * (NN / NQRT) + sub * 128;
  const float* cp = cb + (size_t)j0 * 3;
#pragma unroll 4
  for (int it = 0; it < 128; ++it) {
    int jj = j0 + it;
    float dx = cp[it * 3 + 0] - qx;
    float dy = cp[it * 3 + 1] - qy;
    float dz = cp[it * 3 + 2] - qz;
    float d2 = dx * dx + dy * dy + dz * dz;
    d2 = (jj == iq) ? 3.0e38f : d2;      // exclude self, branchless
    insert8(d2, jj, bd, bi);
  }
#pragma unroll
  for (int k = 0; k < KNBR; k++) {
    pd[sub][qi][k] = bd[k];
    pi[sub][qi][k] = bi[k];
  }
  __syncthreads();
  if (threadIdx.x < 64) {
    float md[KNBR];
    int mi[KNBR];
#pragma unroll
    for (int k = 0; k < KNBR; k++) { md[k] = 3.0e38f; mi[k] = 0; }
    for (int s = 0; s < SUBW; s++) {
#pragma unroll
      for (int k = 0; k < KNBR; k++) {
        // 3e38 sentinels insert as no-ops (strict <); branchless, no break
        insert8(pd[s][qi][k], pi[s][qi][k], md, mi);
      }
    }
    size_t base = ((size_t)(b * NN + iq) * NQRT + quarter) * KNBR;
#pragma unroll
    for (int k = 0; k < KNBR; k++) {
      qd[base + k] = md[k];
      qj[base + k] = mi[k];   // batch-local index
    }
  }
}

// ---------------------------------------------------------------------------
// Kernel B2: merge the NQRT sorted per-quarter lists per query.
// Ascending quarter order = ascending candidate index; strict-< insertion
// reproduces the reference top_k stable tie-break.
// ---------------------------------------------------------------------------
__global__ __launch_bounds__(256) void knn_merge(
    const float* __restrict__ qd, const int* __restrict__ qj,
    int* __restrict__ nbr) {
  int g = blockIdx.x * 256 + threadIdx.x;   // global query id, 0..16383
  int b = g >> 12;
  float md[KNBR];
  int mi[KNBR];
#pragma unroll
  for (int k = 0; k < KNBR; k++) { md[k] = 3.0e38f; mi[k] = 0; }
  size_t base = (size_t)g * NQRT * KNBR;
  for (int q = 0; q < NQRT; q++) {
#pragma unroll
    for (int k = 0; k < KNBR; k++) {
      insert8(qd[base + q * KNBR + k], qj[base + q * KNBR + k], md, mi);
    }
  }
  int* nr = nbr + (size_t)g * KNBR;
#pragma unroll
  for (int k = 0; k < KNBR; k++) nr[k] = b * NN + mi[k];
}

// ---------------------------------------------------------------------------
// Kernel C: gather neighbors, accumulate pre-weight moments, apply fused
// weights, write output. One wave (64 lanes) per node; 4 nodes per block.
//
// Moments per node (432 floats in LDS):
//   S1[32]    @ 0    : sum_e x1[u,:].ev
//   Z0[64][3] @ 32   : sum_e x0[u]*ev[k]
//   P [32][5] @ 224  : sum_e sum_i x1[u,i]*F[i][k]
//   Q [16][3] @ 384  : sum_e sum_a x2[u,a]*F[k][a]   (E2 = F^T)
// F(ev) 3x5, 11 nonzeros, S=1/sqrt(10), T=1/sqrt(30):
//   col0: (S*Y, S*X, 0)  col1: (S*Z, 0, S*X)  col2: (0, S*Z, S*Y)
//   col3: (S*X, -S*Y, 0) col4: (-T*X, -T*Y, 2T*Z)
// ---------------------------------------------------------------------------
__global__ __launch_bounds__(256) void msg_kernel(
    const float* __restrict__ feats, const float* __restrict__ coords,
    const int* __restrict__ nbr, const float* __restrict__ Wf,
    float* __restrict__ out) {
  __shared__ float fbuf[4][KNBR * DF];   // 4 x 1920 floats
  __shared__ float accb[4][432];
  __shared__ float sev[4][KNBR][3];
  __shared__ int snb[4][KNBR];

  const int w = threadIdx.x >> 6;   // wave within block -> node slot
  const int u = threadIdx.x & 63;   // lane
  const int node = blockIdx.x * 4 + w;

  if (u < KNBR) {
    int j = nbr[(size_t)node * KNBR + u];
    snb[w][u] = j;
    sev[w][u][0] = coords[j * 3 + 0] - coords[node * 3 + 0];
    sev[w][u][1] = coords[j * 3 + 1] - coords[node * 3 + 1];
    sev[w][u][2] = coords[j * 3 + 2] - coords[node * 3 + 2];
  }
  __syncthreads();

  // stage 8 neighbor feature rows (240 floats each) via float4
  {
    float4* fb4 = (float4*)fbuf[w];
    const float4* gf4 = (const float4*)feats;
#pragma unroll
    for (int it = 0; it < 8; it++) {
      int idx = u + it * 64;
      if (idx < KNBR * (DF / 4)) {
        int e = idx / 60;
        int r = idx - e * 60;
        fb4[idx] = gf4[(size_t)snb[w][e] * 60 + r];
      }
    }
  }
  __syncthreads();

  const float S_ = 0.31622776601683794f;  // 1/sqrt(10)
  const float T_ = 0.18257418583505536f;  // 1/sqrt(30)

  float z0x = 0.f, z0y = 0.f, z0z = 0.f;
  float s1 = 0.f, p0 = 0.f, p1 = 0.f, p2 = 0.f, p3 = 0.f, p4 = 0.f;
  float q0 = 0.f, q1 = 0.f, q2 = 0.f;
  const float* fw = fbuf[w];

#pragma unroll
  for (int e = 0; e < KNBR; e++) {
    float X = sev[w][e][0], Y = sev[w][e][1], Z = sev[w][e][2];
    float sxv = S_ * X, syv = S_ * Y, szv = S_ * Z;
    float txv = T_ * X, tyv = T_ * Y, t2z = 2.f * T_ * Z;
    const float* fr = fw + e * DF;
    float x0v = fr[u];
    z0x += x0v * X;
    z0y += x0v * Y;
    z0z += x0v * Z;
    if (u < 32) {
      float a0 = fr[64 + 3 * u], a1 = fr[65 + 3 * u], a2 = fr[66 + 3 * u];
      s1 += a0 * X + a1 * Y + a2 * Z;
      p0 += a0 * syv + a1 * sxv;
      p1 += a0 * szv + a2 * sxv;
      p2 += a1 * szv + a2 * syv;
      p3 += a0 * sxv - a1 * syv;
      p4 += a2 * t2z - a0 * txv - a1 * tyv;
      if (u < 16) {
        float b0 = fr[160 + 5 * u], b1 = fr[161 + 5 * u], b2 = fr[162 + 5 * u];
        float b3 = fr[163 + 5 * u], b4 = fr[164 + 5 * u];
        q0 += b0 * syv + b1 * szv + b3 * sxv - b4 * txv;
        q1 += b0 * sxv + b2 * szv - b3 * syv - b4 * tyv;
        q2 += b1 * sxv + b2 * syv + b4 * t2z;
      }
    }
  }

  float* A = accb[w];
  A[32 + 3 * u + 0] = z0x;
  A[32 + 3 * u + 1] = z0y;
  A[32 + 3 * u + 2] = z0z;
  if (u < 32) {
    A[u] = s1;
    float* pp = A + 224 + 5 * u;
    pp[0] = p0; pp[1] = p1; pp[2] = p2; pp[3] = p3; pp[4] = p4;
  }
  if (u < 16) {
    float* qq = A + 384 + 3 * u;
    qq[0] = q0; qq[1] = q1; qq[2] = q2;
  }
  __syncthreads();

  const float* WA = Wf;          // 32x64
  const float* WB = Wf + 2048;   // 64x32
  const float* WC = Wf + 4096;   // 16x32
  const float* WD = Wf + 4608;   // 32x16
  float* orow = out + (size_t)node * DF;

  // y0[u] = sum_m S1[m] * WA[m][u]
  {
    float a = 0.f;
#pragma unroll
    for (int m = 0; m < 32; m++) a += A[m] * WA[m * 64 + u];
    orow[u] = a;
  }
  // y1 flat [w1*3+k], 96 outputs (two passes over 64 lanes)
#pragma unroll
  for (int m0 = 0; m0 < 96; m0 += 64) {
    int m = m0 + u;
    if (m < 96) {
      int w1 = m / 3, k = m - w1 * 3;
      float a = 0.f;
#pragma unroll
      for (int t = 0; t < 64; t++) a += A[32 + 3 * t + k] * WB[t * 32 + w1];
#pragma unroll
      for (int t = 0; t < 16; t++) a += A[384 + 3 * t + k] * WC[t * 32 + w1];
      orow[64 + m] = a;
    }
  }
  // y2 flat [w2*5+k], 80 outputs (two passes over 64 lanes)
#pragma unroll
  for (int m0 = 0; m0 < 80; m0 += 64) {
    int m = m0 + u;
    if (m < 80) {
      int w2 = m / 5, k = m - w2 * 5;
      float a = 0.f;
#pragma unroll
      for (int t = 0; t < 32; t++) a += A[224 + 5 * t + k] * WD[t * 16 + w2];
      orow[160 + m] = a;
    }
  }
}

// ---------------------------------------------------------------------------
extern "C" void kernel_launch(void* const* d_in, const int* in_sizes, int n_in,
                              void* d_out, int out_size, void* d_ws,
                              size_t ws_size, hipStream_t stream) {
  const float* feats  = (const float*)d_in[0];
  const float* coords = (const float*)d_in[1];
  const float* W1 = (const float*)d_in[2];
  const float* W2 = (const float*)d_in[3];
  const float* W3 = (const float*)d_in[4];
  const float* W4 = (const float*)d_in[5];
  const float* L0 = (const float*)d_in[6];
  const float* L1 = (const float*)d_in[7];
  const float* L2 = (const float*)d_in[8];
  float* out = (float*)d_out;

  // workspace layout (floats): Wf[5120] | nbr[131072 ints] | qd[524288] | qj[524288 ints]
  float* Wf  = (float*)d_ws;
  int*   nbr = (int*)((float*)d_ws + 5120);
  float* qd  = (float*)d_ws + 5120 + 131072;
  int*   qj  = (int*)((float*)d_ws + 5120 + 131072 + 524288);

  fuse_w<<<20, 256, 0, stream>>>(W1, W2, W3, W4, L0, L1, L2, Wf);
  knn_scan<<<1024, 512, 0, stream>>>(coords, qd, qj);
  knn_merge<<<64, 256, 0, stream>>>(qd, qj, nbr);
  msg_kernel<<<4096, 256, 0, stream>>>(feats, coords, nbr, Wf, out);
}

// Round 7
// 216.542 us; speedup vs baseline: 4.6798x; 4.6798x over previous
//
#include <hip/hip_runtime.h>

#define NN   4096
#define KNBR 8
#define DF   240
#define SUBW 8    // candidate sub-ranges (waves) per kNN block
#define QPB  64   // queries per kNN block
#define NQRT 4    // candidate quarters

// Distance-only sorted-top-8 insert: pure med3/min chain, NO masks, NO bools.
// Inserting v into sorted ascending t[0..7] (dropping t[7]):
//   t[k] = med3(t[k-1], t[k], v), descending k; t[0] = min(t[0], v).
__device__ __forceinline__ void insD(float v, float t[KNBR]) {
#pragma unroll
  for (int k = KNBR - 1; k >= 1; k--)
    t[k] = __builtin_amdgcn_fmed3f(t[k - 1], t[k], v);
  t[0] = fminf(t[0], v);
}

// (distance,index) sorted-top-8 insert — R5's proven formulation (VGPR 24):
// nested ternaries, masks consumed immediately, strict < (stable for
// ascending-j insertion order).
__device__ __forceinline__ void insertDI(float d2, int j, float bd[KNBR],
                                         int bi[KNBR]) {
#pragma unroll
  for (int k = KNBR - 1; k >= 1; k--) {
    bool mk  = d2 < bd[k];
    bool mk1 = d2 < bd[k - 1];
    bd[k] = mk ? (mk1 ? bd[k - 1] : d2) : bd[k];
    bi[k] = mk ? (mk1 ? bi[k - 1] : j) : bi[k];
  }
  bool m0 = d2 < bd[0];
  bd[0] = m0 ? d2 : bd[0];
  bi[0] = m0 ? j : bi[0];
}

// ---------------------------------------------------------------------------
// Kernel A: fuse weights.
//   WA = sA * (W2 @ L0)   (32x64)   ws[0..2048)
//   WB = sB * (W1 @ L1)   (64x32)   ws[2048..4096)
//   WC = sC * (W4 @ L1)   (16x32)   ws[4096..4608)
//   WD = sD * (W3 @ L2)   (32x16)   ws[4608..5120)
// ---------------------------------------------------------------------------
__global__ __launch_bounds__(256) void fuse_w(
    const float* __restrict__ W1, const float* __restrict__ W2,
    const float* __restrict__ W3, const float* __restrict__ W4,
    const float* __restrict__ L0, const float* __restrict__ L1,
    const float* __restrict__ L2, float* __restrict__ Wf) {
  const float sA = 0.012757759076995719f;  // sqrt(1/96)/8
  const float sB = 0.019764235376052370f;  // 1/sqrt(80*32)
  const float sC = 0.034232659844072875f;  // sqrt(3)/sqrt(80*32)
  const float sD = 0.098821176880261850f;  // sqrt(5/32)/4
  int idx = blockIdx.x * 256 + threadIdx.x;
  if (idx < 2048) {                       // WA: (32x64) = W2(32x64) @ L0(64x64)
    int u = idx >> 6, c = idx & 63;
    float a = 0.f;
#pragma unroll 8
    for (int m = 0; m < 64; m++) a += W2[u * 64 + m] * L0[m * 64 + c];
    Wf[idx] = sA * a;
  } else if (idx < 4096) {                // WB: (64x32) = W1(64x32) @ L1(32x32)
    int t = idx - 2048;
    int u = t >> 5, c = t & 31;
    float a = 0.f;
#pragma unroll 8
    for (int m = 0; m < 32; m++) a += W1[u * 32 + m] * L1[m * 32 + c];
    Wf[idx] = sB * a;
  } else if (idx < 4608) {                // WC: (16x32) = W4(16x32) @ L1(32x32)
    int t = idx - 4096;
    int u = t >> 5, c = t & 31;
    float a = 0.f;
#pragma unroll 8
    for (int m = 0; m < 32; m++) a += W4[u * 32 + m] * L1[m * 32 + c];
    Wf[idx] = sC * a;
  } else if (idx < 5120) {                // WD: (32x16) = W3(32x16) @ L2(16x16)
    int t = idx - 4608;
    int u = t >> 4, c = t & 15;
    float a = 0.f;
#pragma unroll 8
    for (int m = 0; m < 16; m++) a += W3[u * 16 + m] * L2[m * 16 + c];
    Wf[idx] = sD * a;
  }
}

// ---------------------------------------------------------------------------
// Kernel B1: distance-only kNN scan (pass 1). grid = B*64*NQRT = 1024 blocks,
// 512 threads. lane = query, wave = 128-candidate sub-range. Hot loop is
// ~19 VALU/iter (6 dist + 8 med3 + self-mask + overhead), no lane masks.
// Wave 0 merges the 8 sub-lists -> per-(query,quarter) sorted top-8 DISTANCES.
// ---------------------------------------------------------------------------
__global__ __launch_bounds__(512) void knn_scan_d(
    const float* __restrict__ coords, float* __restrict__ qd) {
  __shared__ float pd[SUBW][QPB][KNBR + 1];        // stride-9 pad
  const int blk = blockIdx.x;
  const int b = blk >> 8;
  const int chunk = (blk >> 2) & 63;
  const int quarter = blk & 3;
  const int qi  = threadIdx.x & 63;
  const int sub = threadIdx.x >> 6;
  const int iq  = chunk * 64 + qi;
  const float* cb = coords + (size_t)b * NN * 3;
  const float qx = cb[iq * 3 + 0], qy = cb[iq * 3 + 1], qz = cb[iq * 3 + 2];
  float td[KNBR];
#pragma unroll
  for (int k = 0; k < KNBR; k++) td[k] = 3.0e38f;
  const int j0 = quarter * (NN / NQRT) + sub * 128;
  const float* cp = cb + (size_t)j0 * 3;
#pragma unroll 4
  for (int it = 0; it < 128; ++it) {
    float dx = cp[it * 3 + 0] - qx;
    float dy = cp[it * 3 + 1] - qy;
    float dz = cp[it * 3 + 2] - qz;
    float d2 = dx * dx + dy * dy + dz * dz;
    d2 = (j0 + it == iq) ? 3.0e38f : d2;   // exclude self
    insD(d2, td);
  }
#pragma unroll
  for (int k = 0; k < KNBR; k++) pd[sub][qi][k] = td[k];
  __syncthreads();
  if (threadIdx.x < 64) {
    float md[KNBR];
#pragma unroll
    for (int k = 0; k < KNBR; k++) md[k] = 3.0e38f;
    for (int s = 0; s < SUBW; s++) {
#pragma unroll
      for (int k = 0; k < KNBR; k++) insD(pd[s][qi][k], md);
    }
    size_t base = ((size_t)(b * NN + iq) * NQRT + quarter) * KNBR;
#pragma unroll
    for (int k = 0; k < KNBR; k++) qd[base + k] = md[k];
  }
}

// ---------------------------------------------------------------------------
// Kernel B2: per-query threshold = global 8th-smallest distance
// (merge the NQRT per-quarter sorted distance lists).
// ---------------------------------------------------------------------------
__global__ __launch_bounds__(256) void knn_thr(
    const float* __restrict__ qd, float* __restrict__ thr) {
  int g = blockIdx.x * 256 + threadIdx.x;   // global query id
  float md[KNBR];
#pragma unroll
  for (int k = 0; k < KNBR; k++) md[k] = 3.0e38f;
  size_t base = (size_t)g * NQRT * KNBR;
#pragma unroll
  for (int i = 0; i < NQRT * KNBR; i++) insD(qd[base + i], md);
  thr[g] = md[KNBR - 1];
}

// ---------------------------------------------------------------------------
// Kernel B3: collect (pass 2). Same decomposition as pass 1. Re-scan; only
// candidates with d2 <= thr (expected 8 per query, ~12.5% any-lane rate per
// wave-iter) enter the guarded insertDI. Partials -> LDS -> wave 0 merges
// (ascending sub = ascending j, strict <) -> per-(query,quarter) (d,i) top-8.
// Exactness: {d2 <= thr} contains the top-8 set incl. ties; ascending-j
// strict-< insertion drops only largest-j ties beyond 8, same as reference.
// ---------------------------------------------------------------------------
__global__ __launch_bounds__(512) void knn_collect(
    const float* __restrict__ coords, const float* __restrict__ thr,
    float* __restrict__ qd2, int* __restrict__ qj2) {
  __shared__ float pd[SUBW][QPB][KNBR + 1];        // stride-9 pad
  __shared__ int   pi[SUBW][QPB][KNBR + 1];
  const int blk = blockIdx.x;
  const int b = blk >> 8;
  const int chunk = (blk >> 2) & 63;
  const int quarter = blk & 3;
  const int qi  = threadIdx.x & 63;
  const int sub = threadIdx.x >> 6;
  const int iq  = chunk * 64 + qi;
  const float* cb = coords + (size_t)b * NN * 3;
  const float qx = cb[iq * 3 + 0], qy = cb[iq * 3 + 1], qz = cb[iq * 3 + 2];
  const float tq = thr[b * NN + iq];
  float bd[KNBR];
  int bi[KNBR];
#pragma unroll
  for (int k = 0; k < KNBR; k++) { bd[k] = 3.0e38f; bi[k] = 0; }
  const int j0 = quarter * (NN / NQRT) + sub * 128;
  const float* cp = cb + (size_t)j0 * 3;
#pragma unroll 2
  for (int it = 0; it < 128; ++it) {
    int jj = j0 + it;
    float dx = cp[it * 3 + 0] - qx;
    float dy = cp[it * 3 + 1] - qy;
    float dz = cp[it * 3 + 2] - qz;
    float d2 = dx * dx + dy * dy + dz * dz;
    d2 = (jj == iq) ? 3.0e38f : d2;
    if (d2 <= tq) insertDI(d2, jj, bd, bi);   // rare: ~12.5% any-lane
  }
#pragma unroll
  for (int k = 0; k < KNBR; k++) {
    pd[sub][qi][k] = bd[k];
    pi[sub][qi][k] = bi[k];
  }
  __syncthreads();
  if (threadIdx.x < 64) {
    float md[KNBR];
    int mi[KNBR];
#pragma unroll
    for (int k = 0; k < KNBR; k++) { md[k] = 3.0e38f; mi[k] = 0; }
    for (int s = 0; s < SUBW; s++) {
#pragma unroll
      for (int k = 0; k < KNBR; k++) {
        float vd = pd[s][qi][k];
        if (vd < md[KNBR - 1]) insertDI(vd, pi[s][qi][k], md, mi);
      }
    }
    size_t base = ((size_t)(b * NN + iq) * NQRT + quarter) * KNBR;
#pragma unroll
    for (int k = 0; k < KNBR; k++) {
      qd2[base + k] = md[k];
      qj2[base + k] = mi[k];   // batch-local index (sentinel slots = 3e38)
    }
  }
}

// ---------------------------------------------------------------------------
// Kernel B4: merge the NQRT sorted per-quarter (d,i) lists per query.
// Ascending quarter order = ascending candidate index; strict-< insertion
// reproduces the reference top_k stable tie-break. Sentinels skipped by guard.
// ---------------------------------------------------------------------------
__global__ __launch_bounds__(256) void knn_merge(
    const float* __restrict__ qd2, const int* __restrict__ qj2,
    int* __restrict__ nbr) {
  int g = blockIdx.x * 256 + threadIdx.x;   // global query id
  int b = g >> 12;
  float md[KNBR];
  int mi[KNBR];
#pragma unroll
  for (int k = 0; k < KNBR; k++) { md[k] = 3.0e38f; mi[k] = 0; }
  size_t base = (size_t)g * NQRT * KNBR;
  for (int q = 0; q < NQRT; q++) {
#pragma unroll
    for (int k = 0; k < KNBR; k++) {
      float vd = qd2[base + q * KNBR + k];
      if (vd < md[KNBR - 1]) insertDI(vd, qj2[base + q * KNBR + k], md, mi);
    }
  }
  int* nr = nbr + (size_t)g * KNBR;
#pragma unroll
  for (int k = 0; k < KNBR; k++) nr[k] = b * NN + mi[k];
}

// ---------------------------------------------------------------------------
// Kernel C: gather neighbors, accumulate pre-weight moments, apply fused
// weights, write output. One wave (64 lanes) per node; 4 nodes per block.
//
// Moments per node (432 floats in LDS):
//   S1[32]    @ 0    : sum_e x1[u,:].ev
//   Z0[64][3] @ 32   : sum_e x0[u]*ev[k]
//   P [32][5] @ 224  : sum_e sum_i x1[u,i]*F[i][k]
//   Q [16][3] @ 384  : sum_e sum_a x2[u,a]*F[k][a]   (E2 = F^T)
// F(ev) 3x5, 11 nonzeros, S=1/sqrt(10), T=1/sqrt(30):
//   col0: (S*Y, S*X, 0)  col1: (S*Z, 0, S*X)  col2: (0, S*Z, S*Y)
//   col3: (S*X, -S*Y, 0) col4: (-T*X, -T*Y, 2T*Z)
// ---------------------------------------------------------------------------
__global__ __launch_bounds__(256) void msg_kernel(
    const float* __restrict__ feats, const float* __restrict__ coords,
    const int* __restrict__ nbr, const float* __restrict__ Wf,
    float* __restrict__ out) {
  __shared__ float fbuf[4][KNBR * DF];   // 4 x 1920 floats
  __shared__ float accb[4][432];
  __shared__ float sev[4][KNBR][3];
  __shared__ int snb[4][KNBR];

  const int w = threadIdx.x >> 6;   // wave within block -> node slot
  const int u = threadIdx.x & 63;   // lane
  const int node = blockIdx.x * 4 + w;

  if (u < KNBR) {
    int j = nbr[(size_t)node * KNBR + u];
    snb[w][u] = j;
    sev[w][u][0] = coords[j * 3 + 0] - coords[node * 3 + 0];
    sev[w][u][1] = coords[j * 3 + 1] - coords[node * 3 + 1];
    sev[w][u][2] = coords[j * 3 + 2] - coords[node * 3 + 2];
  }
  __syncthreads();

  // stage 8 neighbor feature rows (240 floats each) via float4
  {
    float4* fb4 = (float4*)fbuf[w];
    const float4* gf4 = (const float4*)feats;
#pragma unroll
    for (int it = 0; it < 8; it++) {
      int idx = u + it * 64;
      if (idx < KNBR * (DF / 4)) {
        int e = idx / 60;
        int r = idx - e * 60;
        fb4[idx] = gf4[(size_t)snb[w][e] * 60 + r];
      }
    }
  }
  __syncthreads();

  const float S_ = 0.31622776601683794f;  // 1/sqrt(10)
  const float T_ = 0.18257418583505536f;  // 1/sqrt(30)

  float z0x = 0.f, z0y = 0.f, z0z = 0.f;
  float s1 = 0.f, p0 = 0.f, p1 = 0.f, p2 = 0.f, p3 = 0.f, p4 = 0.f;
  float q0 = 0.f, q1 = 0.f, q2 = 0.f;
  const float* fw = fbuf[w];

#pragma unroll
  for (int e = 0; e < KNBR; e++) {
    float X = sev[w][e][0], Y = sev[w][e][1], Z = sev[w][e][2];
    float sxv = S_ * X, syv = S_ * Y, szv = S_ * Z;
    float txv = T_ * X, tyv = T_ * Y, t2z = 2.f * T_ * Z;
    const float* fr = fw + e * DF;
    float x0v = fr[u];
    z0x += x0v * X;
    z0y += x0v * Y;
    z0z += x0v * Z;
    if (u < 32) {
      float a0 = fr[64 + 3 * u], a1 = fr[65 + 3 * u], a2 = fr[66 + 3 * u];
      s1 += a0 * X + a1 * Y + a2 * Z;
      p0 += a0 * syv + a1 * sxv;
      p1 += a0 * szv + a2 * sxv;
      p2 += a1 * szv + a2 * syv;
      p3 += a0 * sxv - a1 * syv;
      p4 += a2 * t2z - a0 * txv - a1 * tyv;
      if (u < 16) {
        float b0 = fr[160 + 5 * u], b1 = fr[161 + 5 * u], b2 = fr[162 + 5 * u];
        float b3 = fr[163 + 5 * u], b4 = fr[164 + 5 * u];
        q0 += b0 * syv + b1 * szv + b3 * sxv - b4 * txv;
        q1 += b0 * sxv + b2 * szv - b3 * syv - b4 * tyv;
        q2 += b1 * sxv + b2 * syv + b4 * t2z;
      }
    }
  }

  float* A = accb[w];
  A[32 + 3 * u + 0] = z0x;
  A[32 + 3 * u + 1] = z0y;
  A[32 + 3 * u + 2] = z0z;
  if (u < 32) {
    A[u] = s1;
    float* pp = A + 224 + 5 * u;
    pp[0] = p0; pp[1] = p1; pp[2] = p2; pp[3] = p3; pp[4] = p4;
  }
  if (u < 16) {
    float* qq = A + 384 + 3 * u;
    qq[0] = q0; qq[1] = q1; qq[2] = q2;
  }
  __syncthreads();

  const float* WA = Wf;          // 32x64
  const float* WB = Wf + 2048;   // 64x32
  const float* WC = Wf + 4096;   // 16x32
  const float* WD = Wf + 4608;   // 32x16
  float* orow = out + (size_t)node * DF;

  // y0[u] = sum_m S1[m] * WA[m][u]
  {
    float a = 0.f;
#pragma unroll
    for (int m = 0; m < 32; m++) a += A[m] * WA[m * 64 + u];
    orow[u] = a;
  }
  // y1 flat [w1*3+k], 96 outputs (two passes over 64 lanes)
#pragma unroll
  for (int m0 = 0; m0 < 96; m0 += 64) {
    int m = m0 + u;
    if (m < 96) {
      int w1 = m / 3, k = m - w1 * 3;
      float a = 0.f;
#pragma unroll
      for (int t = 0; t < 64; t++) a += A[32 + 3 * t + k] * WB[t * 32 + w1];
#pragma unroll
      for (int t = 0; t < 16; t++) a += A[384 + 3 * t + k] * WC[t * 32 + w1];
      orow[64 + m] = a;
    }
  }
  // y2 flat [w2*5+k], 80 outputs (two passes over 64 lanes)
#pragma unroll
  for (int m0 = 0; m0 < 80; m0 += 64) {
    int m = m0 + u;
    if (m < 80) {
      int w2 = m / 5, k = m - w2 * 5;
      float a = 0.f;
#pragma unroll
      for (int t = 0; t < 32; t++) a += A[224 + 5 * t + k] * WD[t * 16 + w2];
      orow[160 + m] = a;
    }
  }
}

// ---------------------------------------------------------------------------
extern "C" void kernel_launch(void* const* d_in, const int* in_sizes, int n_in,
                              void* d_out, int out_size, void* d_ws,
                              size_t ws_size, hipStream_t stream) {
  const float* feats  = (const float*)d_in[0];
  const float* coords = (const float*)d_in[1];
  const float* W1 = (const float*)d_in[2];
  const float* W2 = (const float*)d_in[3];
  const float* W3 = (const float*)d_in[4];
  const float* W4 = (const float*)d_in[5];
  const float* L0 = (const float*)d_in[6];
  const float* L1 = (const float*)d_in[7];
  const float* L2 = (const float*)d_in[8];
  float* out = (float*)d_out;

  // workspace (floats): Wf[5120] | nbr[131072 i] | qd[524288] (reused as qd2)
  //                     | thr[16384] | qj2[524288 i]   -> ~4.6 MB total
  float* Wf  = (float*)d_ws;
  int*   nbr = (int*)((float*)d_ws + 5120);
  float* qd  = (float*)d_ws + 5120 + 131072;
  float* thr = (float*)d_ws + 5120 + 131072 + 524288;
  int*   qj2 = (int*)((float*)d_ws + 5120 + 131072 + 524288 + 16384);

  fuse_w<<<20, 256, 0, stream>>>(W1, W2, W3, W4, L0, L1, L2, Wf);
  knn_scan_d<<<1024, 512, 0, stream>>>(coords, qd);
  knn_thr<<<64, 256, 0, stream>>>(qd, thr);
  knn_collect<<<1024, 512, 0, stream>>>(coords, thr, qd, qj2);  // qd2 aliases qd
  knn_merge<<<64, 256, 0, stream>>>(qd, qj2, nbr);
  msg_kernel<<<4096, 256, 0, stream>>>(feats, coords, nbr, Wf, out);
}